// Round 1
// baseline (704.696 us; speedup 1.0000x reference)
//
#include <hip/hip_runtime.h>

// Problem constants (B=8, H=4096, C=512, GROUPS=4)
constexpr int D        = 128;        // d = C/GROUPS
constexpr int NE       = 512;        // n_embed
constexpr int NROWS    = 131072;     // B*H*GROUPS
constexpr int MROWS    = 32768;      // B*H
constexpr int CC       = 512;        // C
constexpr int OUT_ELEMS = 16777216;  // MROWS*CC

// ws layout (floats): [0] = diff accumulator, [16..16+NE) = ||e_j||^2

// ---------------------------------------------------------------------------
// Kernel 0: per-code squared norms + zero the diff accumulator.
// grid = NE blocks x 64 threads (one wave per code).
__global__ void enorm_zero_kernel(const float* __restrict__ embed,
                                  float* __restrict__ ws) {
    const int c = blockIdx.x;
    const int lane = threadIdx.x;
    float v0 = embed[c * D + lane];
    float v1 = embed[c * D + 64 + lane];
    float s = v0 * v0 + v1 * v1;
#pragma unroll
    for (int off = 32; off; off >>= 1) s += __shfl_down(s, off);
    if (lane == 0) {
        ws[16 + c] = s;
        if (c == 0) ws[0] = 0.0f;
    }
}

// ---------------------------------------------------------------------------
// Kernel 1: distance GEMM + argmin + loss partial sums.
// 64 rows/block, 512 codes in 16 chunks of 32. 256 threads, 4x2 micro-tile.
// LDS stride 132 floats: float4-aligned (528B) and bank-conflict-free.
#define XS_STRIDE 132
#define XS_S4 33

__launch_bounds__(256, 2)
__global__ void argmin_kernel(const float* __restrict__ z,
                              const float* __restrict__ embed,
                              float* __restrict__ ws,
                              float* __restrict__ ind_f) {
    __shared__ float Xs[64 * XS_STRIDE];   // 33792 B
    __shared__ float Es[32 * XS_STRIDE];   // 16896 B
    __shared__ float xpart[64 * 4];
    __shared__ float xnorm_s[64];

    const int tid = threadIdx.x;
    const int rowbase = blockIdx.x * 64;
    const int tx = tid & 15;   // code sub-index
    const int ty = tid >> 4;   // row sub-index

    // Stage X tile (64 rows x 128) + per-row squared-norm partials.
    {
        const int r = tid >> 2, seg = tid & 3;
        const float4* src = (const float4*)(z + (size_t)(rowbase + r) * D + seg * 32);
        float4* dst = (float4*)&Xs[r * XS_STRIDE + seg * 32];
        float ss = 0.f;
#pragma unroll
        for (int q = 0; q < 8; q++) {
            float4 v = src[q];
            dst[q] = v;
            ss += v.x * v.x + v.y * v.y + v.z * v.z + v.w * v.w;
        }
        xpart[r * 4 + seg] = ss;
    }
    __syncthreads();
    if (tid < 64)
        xnorm_s[tid] = xpart[tid * 4] + xpart[tid * 4 + 1] +
                       xpart[tid * 4 + 2] + xpart[tid * 4 + 3];

    float minv[4];
    int   mini[4];
#pragma unroll
    for (int i = 0; i < 4; i++) { minv[i] = 3.4e38f; mini[i] = 0; }

    for (int chunk = 0; chunk < 16; chunk++) {
        const int cbase = chunk * 32;
        // Stage E chunk (32 codes x 128).
        {
            const int cl = tid >> 3, seg = tid & 7;
            const float4* src = (const float4*)(embed + (cbase + cl) * D + seg * 16);
            float4* dst = (float4*)&Es[cl * XS_STRIDE + seg * 16];
#pragma unroll
            for (int q = 0; q < 4; q++) dst[q] = src[q];
        }
        __syncthreads();

        float acc[4][2];
#pragma unroll
        for (int i = 0; i < 4; i++) { acc[i][0] = 0.f; acc[i][1] = 0.f; }

        const float4* xs4 = (const float4*)Xs;
        const float4* es4 = (const float4*)Es;
#pragma unroll 4
        for (int kk = 0; kk < 32; kk++) {
            float4 a[4], b[2];
#pragma unroll
            for (int i = 0; i < 4; i++) a[i] = xs4[(ty + 16 * i) * XS_S4 + kk];
#pragma unroll
            for (int j = 0; j < 2; j++) b[j] = es4[(tx + 16 * j) * XS_S4 + kk];
#pragma unroll
            for (int i = 0; i < 4; i++)
#pragma unroll
                for (int j = 0; j < 2; j++)
                    acc[i][j] += a[i].x * b[j].x + a[i].y * b[j].y +
                                 a[i].z * b[j].z + a[i].w * b[j].w;
        }

        // dist proxy: ||e||^2 - 2 x.e  (||x||^2 constant per row)
#pragma unroll
        for (int j = 0; j < 2; j++) {
            const int c = cbase + tx + 16 * j;
            const float en = ws[16 + c];
#pragma unroll
            for (int i = 0; i < 4; i++) {
                const float p = en - 2.0f * acc[i][j];
                if (p < minv[i]) { minv[i] = p; mini[i] = c; }  // strict < keeps first index
            }
        }
        __syncthreads();
    }

    // Reduce across the 16 tx lanes (consecutive lanes in-wave) per row.
    float dsum = 0.f;
#pragma unroll
    for (int i = 0; i < 4; i++) {
        float v = minv[i]; int ii = mini[i];
#pragma unroll
        for (int off = 8; off; off >>= 1) {
            float ov = __shfl_down(v, off, 16);
            int   oi = __shfl_down(ii, off, 16);
            if (ov < v || (ov == v && oi < ii)) { v = ov; ii = oi; }
        }
        if (tx == 0) {
            const int r = ty + 16 * i;
            ind_f[rowbase + r] = (float)ii;
            dsum += xnorm_s[r] + v;   // ||x-e||^2 for this row
        }
    }
    // Wave-sum the per-row distances, one atomic per wave.
#pragma unroll
    for (int off = 32; off; off >>= 1) dsum += __shfl_down(dsum, off);
    if ((tid & 63) == 0) atomicAdd(ws, dsum);
}

// ---------------------------------------------------------------------------
// Kernel 2: out[m, c] = sum_k z_q[m, k] * proj_w[c, k] + proj_b[c]
// z_q gathered on the fly from embed via ind. 64x64 tile, K-chunks of 64.
#define AS_STRIDE 68
#define AS_S4 17

__launch_bounds__(256, 4)
__global__ void proj_kernel(const float* __restrict__ embed,
                            const float* __restrict__ projw,
                            const float* __restrict__ projb,
                            const float* __restrict__ ind_f,
                            float* __restrict__ out) {
    __shared__ float As[64 * AS_STRIDE];   // 17408 B
    __shared__ float Bs[64 * AS_STRIDE];   // 17408 B
    const int tid = threadIdx.x;
    const int cbase = blockIdx.x * 64;   // gridDim.x = 8
    const int mbase = blockIdx.y * 64;   // gridDim.y = 512
    const int tx = tid & 15, ty = tid >> 4;
    const int r = tid >> 2, seg = tid & 3;

    float acc[4][4];
#pragma unroll
    for (int i = 0; i < 4; i++)
#pragma unroll
        for (int j = 0; j < 4; j++) acc[i][j] = 0.f;

    for (int kb = 0; kb < CC; kb += 64) {
        const int g = kb >> 7;                         // group is constant per chunk
        const int idx = (int)ind_f[(mbase + r) * 4 + g];
        const float4* asrc = (const float4*)(embed + idx * D + (kb & 127) + seg * 16);
        const float4* bsrc = (const float4*)(projw + (size_t)(cbase + r) * CC + kb + seg * 16);
        float4* adst = (float4*)&As[r * AS_STRIDE + seg * 16];
        float4* bdst = (float4*)&Bs[r * AS_STRIDE + seg * 16];
#pragma unroll
        for (int q = 0; q < 4; q++) { adst[q] = asrc[q]; bdst[q] = bsrc[q]; }
        __syncthreads();

        const float4* as4 = (const float4*)As;
        const float4* bs4 = (const float4*)Bs;
#pragma unroll 4
        for (int kk = 0; kk < 16; kk++) {
            float4 a[4], b[4];
#pragma unroll
            for (int i = 0; i < 4; i++) a[i] = as4[(ty + 16 * i) * AS_S4 + kk];
#pragma unroll
            for (int j = 0; j < 4; j++) b[j] = bs4[(tx + 16 * j) * AS_S4 + kk];
#pragma unroll
            for (int i = 0; i < 4; i++)
#pragma unroll
                for (int j = 0; j < 4; j++)
                    acc[i][j] += a[i].x * b[j].x + a[i].y * b[j].y +
                                 a[i].z * b[j].z + a[i].w * b[j].w;
        }
        __syncthreads();
    }

#pragma unroll
    for (int j = 0; j < 4; j++) {
        const int c = cbase + tx + 16 * j;
        const float bias = projb[c];
#pragma unroll
        for (int i = 0; i < 4; i++)
            out[(size_t)(mbase + ty + 16 * i) * CC + c] = acc[i][j] + bias;
    }
}

// ---------------------------------------------------------------------------
__global__ void finalize_kernel(const float* __restrict__ ws,
                                float* __restrict__ diff_out) {
    // diff = 10 * (0.25 + 1.0) * mean((z_q - z_e)^2) = 12.5 * S / (NROWS*D)
    diff_out[0] = 12.5f * ws[0] * (1.0f / 16777216.0f);
}

// ---------------------------------------------------------------------------
extern "C" void kernel_launch(void* const* d_in, const int* in_sizes, int n_in,
                              void* d_out, int out_size, void* d_ws, size_t ws_size,
                              hipStream_t stream) {
    const float* z     = (const float*)d_in[0];
    const float* embed = (const float*)d_in[1];
    const float* projw = (const float*)d_in[2];
    const float* projb = (const float*)d_in[3];

    float* out      = (float*)d_out;
    float* diff_out = out + OUT_ELEMS;          // output 1 (scalar)
    float* ind_f    = out + OUT_ELEMS + 1;      // output 2 (indices as float)
    float* ws       = (float*)d_ws;

    enorm_zero_kernel<<<NE, 64, 0, stream>>>(embed, ws);
    argmin_kernel<<<NROWS / 64, 256, 0, stream>>>(z, embed, ws, ind_f);
    proj_kernel<<<dim3(8, 512), 256, 0, stream>>>(embed, projw, projb, ind_f, out);
    finalize_kernel<<<1, 1, 0, stream>>>(ws, diff_out);
}

// Round 3
// 327.010 us; speedup vs baseline: 2.1550x; 2.1550x over previous
//
#include <hip/hip_runtime.h>

// Problem constants (B=8, H=4096, C=512, GROUPS=4)
constexpr int D         = 128;        // d = C/GROUPS
constexpr int NE        = 512;        // n_embed
constexpr int NROWS     = 131072;     // B*H*GROUPS
constexpr int CC        = 512;        // C
constexpr int OUT_ELEMS = 16777216;   // MROWS*CC

// ws layout (bytes):
//   [0]                : float diff accumulator
//   [1024, +409600)    : Esw - 16 chunks x 25600 B, each chunk (byte offsets):
//        [0,8192)      Eh  (-2E term1, bf16, MFMA A-frag layout)
//        [8192,16384)  Em  (-2E term2)
//        [16384,24576) El  (-2E term3)
//        [24576,25600) en-frag: lanes<32: {e0,e1,e2,0..}, lanes>=32: 0
//   [410624, +4194304) : P[4][512][512] fp32

using short8  = __attribute__((ext_vector_type(8))) short;
using f32x16  = __attribute__((ext_vector_type(16))) float;

static __device__ __forceinline__ unsigned short bf16rn(float x) {
    union { float f; unsigned u; } c; c.f = x;
    unsigned u = c.u;
    return (unsigned short)((u + 0x7FFFu + ((u >> 16) & 1u)) >> 16);
}
static __device__ __forceinline__ float bf16tof(unsigned short h) {
    union { unsigned u; float f; } c; c.u = ((unsigned)h) << 16;
    return c.f;
}

// ---------------------------------------------------------------------------
// Kernel 0: 3-term bf16 split of -2E into MFMA A-frag layout + 3-term split
// of ||e||^2 into the en-frag; zero the diff accumulator.
// grid = 16 blocks (one per 32-code chunk) x 256 threads.
__global__ void eprep_kernel(const float* __restrict__ embed,
                             unsigned short* __restrict__ esw,
                             float* __restrict__ ws_diff) {
    const int chunk = blockIdx.x;
    const int tid = threadIdx.x;
    const int cl = tid >> 3;    // code in chunk (0..31) == A-row == lane&31
    const int seg = tid & 7;    // k-group of 16 (== kk)
    const float* src = embed + (size_t)(chunk * 32 + cl) * D + seg * 16;
    unsigned short* cb = esw + (size_t)chunk * 12800;  // shorts per chunk

    float ss = 0.f;
#pragma unroll
    for (int g2 = 0; g2 < 2; g2++) {       // g2 == h5 (k-half of the MFMA slice)
        float4 a = ((const float4*)src)[g2 * 2 + 0];
        float4 b = ((const float4*)src)[g2 * 2 + 1];
        float v[8] = {a.x, a.y, a.z, a.w, b.x, b.y, b.z, b.w};
        short8 t1, t2, t3;
#pragma unroll
        for (int i = 0; i < 8; i++) {
            ss += v[i] * v[i];
            float m2 = -2.0f * v[i];
            unsigned short h = bf16rn(m2);
            float r1 = m2 - bf16tof(h);
            unsigned short m = bf16rn(r1);
            unsigned short l = bf16rn(r1 - bf16tof(m));
            t1[i] = (short)h; t2[i] = (short)m; t3[i] = (short)l;
        }
        const int idx = seg * 512 + g2 * 256 + cl * 8;
        *(short8*)(cb + idx) = t1;          // Eh
        *(short8*)(cb + 4096 + idx) = t2;   // Em
        *(short8*)(cb + 8192 + idx) = t3;   // El
    }
    // ||e||^2 via 8-lane reduction (threads with same cl are consecutive)
    ss += __shfl_down(ss, 4, 8);
    ss += __shfl_down(ss, 2, 8);
    ss += __shfl_down(ss, 1, 8);
    if (seg == 0) {
        unsigned short e0 = bf16rn(ss);
        float r1 = ss - bf16tof(e0);
        unsigned short e1 = bf16rn(r1);
        unsigned short e2 = bf16rn(r1 - bf16tof(e1));
        short8 en = (short8)0;
        en[0] = (short)e0; en[1] = (short)e1; en[2] = (short)e2;
        *(short8*)(cb + 12288 + cl * 8) = en;
    }
    if (seg == 1) {
        *(short8*)(cb + 12288 + 256 + cl * 8) = (short8)0;  // k=8..15 lanes: zero
    }
    if (chunk == 0 && tid == 0) ws_diff[0] = 0.0f;
}

// ---------------------------------------------------------------------------
// Kernel 1: P[g][j][c] = sum_k E[j,k] * W[c, g*128+k]   (fp32, 134 M MAC)
#define AS_STRIDE 68
#define AS_S4 17

__launch_bounds__(256, 4)
__global__ void pgemm_kernel(const float* __restrict__ embed,
                             const float* __restrict__ projw,
                             float* __restrict__ P) {
    __shared__ float As[64 * AS_STRIDE];
    __shared__ float Bs[64 * AS_STRIDE];
    const int tid = threadIdx.x;
    const int cbase = blockIdx.x * 64;   // 8
    const int jbase = blockIdx.y * 64;   // 8
    const int g = blockIdx.z;            // 4
    const int tx = tid & 15, ty = tid >> 4;
    const int r = tid >> 2, seg = tid & 3;

    float acc[4][4];
#pragma unroll
    for (int i = 0; i < 4; i++)
#pragma unroll
        for (int j = 0; j < 4; j++) acc[i][j] = 0.f;

    for (int kb = 0; kb < D; kb += 64) {
        const float4* asrc = (const float4*)(embed + (size_t)(jbase + r) * D + kb + seg * 16);
        const float4* bsrc = (const float4*)(projw + (size_t)(cbase + r) * CC + g * D + kb + seg * 16);
        float4* adst = (float4*)&As[r * AS_STRIDE + seg * 16];
        float4* bdst = (float4*)&Bs[r * AS_STRIDE + seg * 16];
#pragma unroll
        for (int q = 0; q < 4; q++) { adst[q] = asrc[q]; bdst[q] = bsrc[q]; }
        __syncthreads();

        const float4* as4 = (const float4*)As;
        const float4* bs4 = (const float4*)Bs;
#pragma unroll 4
        for (int kk = 0; kk < 16; kk++) {
            float4 a[4], b[4];
#pragma unroll
            for (int i = 0; i < 4; i++) a[i] = as4[(ty + 16 * i) * AS_S4 + kk];
#pragma unroll
            for (int j = 0; j < 4; j++) b[j] = bs4[(tx + 16 * j) * AS_S4 + kk];
#pragma unroll
            for (int i = 0; i < 4; i++)
#pragma unroll
                for (int j = 0; j < 4; j++)
                    acc[i][j] += a[i].x * b[j].x + a[i].y * b[j].y +
                                 a[i].z * b[j].z + a[i].w * b[j].w;
        }
        __syncthreads();
    }
#pragma unroll
    for (int j = 0; j < 4; j++) {
#pragma unroll
        for (int i = 0; i < 4; i++)
            P[(size_t)g * 262144 + (size_t)(jbase + ty + 16 * i) * CC + cbase + tx + 16 * j] =
                acc[i][j];
    }
}

// ---------------------------------------------------------------------------
// Kernel 2: MFMA argmin. Each wave owns 32 rows; X is loaded from raw fp32 z
// and 3-term bf16-split in-register (exact products; dropped cross terms
// ~2^-25 relative -> same error class as an fp32 dot). 6 MFMA products + 1
// en-MFMA per k-chunk give acc = ||e||^2 - 2 x.e directly.
__global__ __launch_bounds__(256)
void argmin_mfma_kernel(const float* __restrict__ z,
                        const unsigned short* __restrict__ esw,
                        float* __restrict__ ws_diff,
                        float* __restrict__ ind_f) {
    __shared__ uint4 lds4[1600];   // 25600 B: one E chunk
    const int tid = threadIdx.x;
    const int lane = tid & 63;
    const int wave = tid >> 6;
    const int h5 = lane >> 5, l5 = lane & 31;
    const int rb = blockIdx.x * 128 + wave * 32;

    // Load this lane's x row-half and split: B-frag for kk holds
    // X[n=l5][k = kk*16 + h5*8 + j].
    short8 x1[8], x2[8], x3[8];
    float xnrm = 0.f;
    {
        const float* zr = z + (size_t)(rb + l5) * D + h5 * 8;
#pragma unroll
        for (int kk = 0; kk < 8; kk++) {
            float4 a = *(const float4*)(zr + kk * 16);
            float4 b = *(const float4*)(zr + kk * 16 + 4);
            float v[8] = {a.x, a.y, a.z, a.w, b.x, b.y, b.z, b.w};
            short8 t1, t2, t3;
#pragma unroll
            for (int i = 0; i < 8; i++) {
                xnrm += v[i] * v[i];
                unsigned short h = bf16rn(v[i]);
                float r1 = v[i] - bf16tof(h);
                unsigned short m = bf16rn(r1);
                unsigned short l = bf16rn(r1 - bf16tof(m));
                t1[i] = (short)h; t2[i] = (short)m; t3[i] = (short)l;
            }
            x1[kk] = t1; x2[kk] = t2; x3[kk] = t3;
        }
    }
    // ones frag for the en-term (B[k][n]=1 at k=0,1,2)
    short8 ones = (short8)0;
    if (lane < 32) { ones[0] = (short)0x3F80; ones[1] = (short)0x3F80; ones[2] = (short)0x3F80; }

    const int hadd = h5 * 4;
    float minv = 3.0e38f;
    int mini = 0;

#pragma unroll 1
    for (int c16 = 0; c16 < 16; c16++) {
        {   // stage 25600 B chunk
            const uint4* src = (const uint4*)((const char*)esw + (size_t)c16 * 25600);
            for (int u = tid; u < 1600; u += 256) lds4[u] = src[u];
        }
        __syncthreads();
        const char* ldsb = (const char*)lds4;

        f32x16 acc = (f32x16)(0.0f);
        {   // en-term: acc[code i][col j] += ||e_i||^2
            short8 aen = *(const short8*)(ldsb + 24576 + h5 * 512 + l5 * 16);
            acc = __builtin_amdgcn_mfma_f32_32x32x16_bf16(aen, ones, acc, 0, 0, 0);
        }
#pragma unroll
        for (int kk = 0; kk < 8; kk++) {
            const int fo = kk * 1024 + h5 * 512 + l5 * 16;
            short8 e1 = *(const short8*)(ldsb + fo);
            short8 e2 = *(const short8*)(ldsb + 8192 + fo);
            short8 e3 = *(const short8*)(ldsb + 16384 + fo);
            // small terms first (marginal accumulation-order benefit)
            acc = __builtin_amdgcn_mfma_f32_32x32x16_bf16(e2, x2[kk], acc, 0, 0, 0);
            acc = __builtin_amdgcn_mfma_f32_32x32x16_bf16(e1, x3[kk], acc, 0, 0, 0);
            acc = __builtin_amdgcn_mfma_f32_32x32x16_bf16(e3, x1[kk], acc, 0, 0, 0);
            acc = __builtin_amdgcn_mfma_f32_32x32x16_bf16(e1, x2[kk], acc, 0, 0, 0);
            acc = __builtin_amdgcn_mfma_f32_32x32x16_bf16(e2, x1[kk], acc, 0, 0, 0);
            acc = __builtin_amdgcn_mfma_f32_32x32x16_bf16(e1, x1[kk], acc, 0, 0, 0);
        }
        __syncthreads();   // before next stage overwrites LDS

        // running argmin; scan order monotone in code index within a lane
        const int cb = c16 * 32 + hadd;
#pragma unroll
        for (int r = 0; r < 16; r++) {
            float p = acc[r];
            int cand = cb + (r & 3) + 8 * (r >> 2);
            if (p < minv) { minv = p; mini = cand; }  // strict < keeps first idx
        }
    }

    // merge the two half-wave code sets for the same x-row (col = lane&31)
    {
        float ov = __shfl_xor(minv, 32);
        int oi = __shfl_xor(mini, 32);
        if (ov < minv || (ov == minv && oi < mini)) { minv = ov; mini = oi; }
    }
    if (lane < 32) ind_f[rb + l5] = (float)mini;

    // diff partial: ||x||^2 (both halves) + min(||e||^2 - 2x.e), lanes<32 only
    float xfull = xnrm + __shfl_xor(xnrm, 32);
    float v = (lane < 32) ? (xfull + minv) : 0.0f;
#pragma unroll
    for (int off = 32; off; off >>= 1) v += __shfl_down(v, off);
    if (lane == 0) atomicAdd(ws_diff, v);
}

// ---------------------------------------------------------------------------
// Kernel 3: out[m,c] = sum_g P[g][ind[m,g]][c] + b[c]
__global__ void apply_kernel(const float* __restrict__ P,
                             const float* __restrict__ projb,
                             const float* __restrict__ ind_f,
                             float* __restrict__ out) {
    const int tid = threadIdx.x;
    const int m = blockIdx.x * 2 + (tid >> 7);
    const int c4 = tid & 127;

    const float4* pb4 = (const float4*)projb;
    float4 acc = pb4[c4];
    const float4* P4 = (const float4*)P;
#pragma unroll
    for (int g = 0; g < 4; g++) {
        const int ig = (int)ind_f[m * 4 + g];
        float4 p = P4[(size_t)g * 65536 + (size_t)ig * 128 + c4];
        acc.x += p.x; acc.y += p.y; acc.z += p.z; acc.w += p.w;
    }
    ((float4*)out)[(size_t)m * 128 + c4] = acc;
}

// ---------------------------------------------------------------------------
__global__ void finalize_kernel(const float* __restrict__ ws_diff,
                                float* __restrict__ diff_out) {
    // diff = 12.5 * (sum ||x||^2 + sum min(||e||^2 - 2x.e)) / (NROWS*D)
    diff_out[0] = 12.5f * ws_diff[0] * (1.0f / 16777216.0f);
}

// ---------------------------------------------------------------------------
extern "C" void kernel_launch(void* const* d_in, const int* in_sizes, int n_in,
                              void* d_out, int out_size, void* d_ws, size_t ws_size,
                              hipStream_t stream) {
    const float* z     = (const float*)d_in[0];
    const float* embed = (const float*)d_in[1];
    const float* projw = (const float*)d_in[2];
    const float* projb = (const float*)d_in[3];

    float* out      = (float*)d_out;
    float* diff_out = out + OUT_ELEMS;
    float* ind_f    = out + OUT_ELEMS + 1;

    char* wsb = (char*)d_ws;
    float* ws_diff = (float*)wsb;
    unsigned short* esw = (unsigned short*)(wsb + 1024);
    float* P = (float*)(wsb + 410624);

    eprep_kernel<<<16, 256, 0, stream>>>(embed, esw, ws_diff);
    pgemm_kernel<<<dim3(8, 8, 4), 256, 0, stream>>>(embed, projw, P);
    argmin_mfma_kernel<<<NROWS / 128, 256, 0, stream>>>(z, esw, ws_diff, ind_f);
    apply_kernel<<<32768 / 2, 256, 0, stream>>>(P, projb, ind_f, out);
    finalize_kernel<<<1, 1, 0, stream>>>(ws_diff, diff_out);
}

// Round 4
// 230.159 us; speedup vs baseline: 3.0618x; 1.4208x over previous
//
#include <hip/hip_runtime.h>

// Problem constants (B=8, H=4096, C=512, GROUPS=4)
constexpr int D         = 128;        // d = C/GROUPS
constexpr int NE        = 512;        // n_embed
constexpr int NROWS     = 131072;     // B*H*GROUPS
constexpr int CC        = 512;        // C
constexpr int OUT_ELEMS = 16777216;   // MROWS*CC

// ws layout (bytes):
//   [0]                 : float diff accumulator
//   [1024, +2048)       : entab - ||e_j||^2 fp32, 512 floats
//   [4096, +262144)     : esw - 16 chunks x 16384 B:
//        [0,8192)   Eh : fp16(-2E), MFMA A-frag layout
//        [8192,16384) El: fp16((-2E - Eh)*2048)
//   [266240, +4194304)  : P[4][512][512] fp32

using half8  = __attribute__((ext_vector_type(8))) _Float16;
using f32x16 = __attribute__((ext_vector_type(16))) float;

// fp16 min normal: leading term below this is zeroed so the (possibly
// flushed-by-MFMA) denormal carries nothing; residual then holds it all.
#define F16_MINNORM 6.103515625e-05f

// ---------------------------------------------------------------------------
// Kernel 0: scaled 2-term fp16 split of -2E into MFMA A-frag layout + fp32
// ||e||^2 table; zero the diff accumulator.
// grid = 16 blocks (one per 32-code chunk) x 256 threads.
__global__ void eprep_kernel(const float* __restrict__ embed,
                             unsigned short* __restrict__ esw,
                             float* __restrict__ entab,
                             float* __restrict__ ws_diff) {
    const int chunk = blockIdx.x;
    const int tid = threadIdx.x;
    const int cl = tid >> 3;    // code in chunk (0..31) == A-row == lane&31
    const int seg = tid & 7;    // k-group of 16 (== kk)
    const float* src = embed + (size_t)(chunk * 32 + cl) * D + seg * 16;
    unsigned short* cb = esw + (size_t)chunk * 8192;  // shorts per chunk

    float ss = 0.f;
#pragma unroll
    for (int g2 = 0; g2 < 2; g2++) {       // g2 == h5 (k-half of the MFMA slice)
        float4 a = ((const float4*)src)[g2 * 2 + 0];
        float4 b = ((const float4*)src)[g2 * 2 + 1];
        float v[8] = {a.x, a.y, a.z, a.w, b.x, b.y, b.z, b.w};
        half8 t1, t2;
#pragma unroll
        for (int i = 0; i < 8; i++) {
            ss += v[i] * v[i];
            float m2 = -2.0f * v[i];
            float m2c = (__builtin_fabsf(m2) < F16_MINNORM) ? 0.0f : m2;
            _Float16 h = (_Float16)m2c;
            float r = m2 - (float)h;
            t1[i] = h;
            t2[i] = (_Float16)(r * 2048.0f);   // scaled residual, fp16-normal
        }
        const int idx = seg * 512 + g2 * 256 + cl * 8;
        *(half8*)(cb + idx) = t1;          // Eh
        *(half8*)(cb + 4096 + idx) = t2;   // El
    }
    // ||e||^2 via 8-lane reduction (threads with same cl are consecutive)
    ss += __shfl_down(ss, 4, 8);
    ss += __shfl_down(ss, 2, 8);
    ss += __shfl_down(ss, 1, 8);
    if (seg == 0) entab[chunk * 32 + cl] = ss;
    if (chunk == 0 && tid == 0) ws_diff[0] = 0.0f;
}

// ---------------------------------------------------------------------------
// Kernel 1: P[g][j][c] = sum_k E[j,k] * W[c, g*128+k]   (fp32, 134 M MAC)
#define AS_STRIDE 68
#define AS_S4 17

__launch_bounds__(256, 4)
__global__ void pgemm_kernel(const float* __restrict__ embed,
                             const float* __restrict__ projw,
                             float* __restrict__ P) {
    __shared__ float As[64 * AS_STRIDE];
    __shared__ float Bs[64 * AS_STRIDE];
    const int tid = threadIdx.x;
    const int cbase = blockIdx.x * 64;   // 8
    const int jbase = blockIdx.y * 64;   // 8
    const int g = blockIdx.z;            // 4
    const int tx = tid & 15, ty = tid >> 4;
    const int r = tid >> 2, seg = tid & 3;

    float acc[4][4];
#pragma unroll
    for (int i = 0; i < 4; i++)
#pragma unroll
        for (int j = 0; j < 4; j++) acc[i][j] = 0.f;

    for (int kb = 0; kb < D; kb += 64) {
        const float4* asrc = (const float4*)(embed + (size_t)(jbase + r) * D + kb + seg * 16);
        const float4* bsrc = (const float4*)(projw + (size_t)(cbase + r) * CC + g * D + kb + seg * 16);
        float4* adst = (float4*)&As[r * AS_STRIDE + seg * 16];
        float4* bdst = (float4*)&Bs[r * AS_STRIDE + seg * 16];
#pragma unroll
        for (int q = 0; q < 4; q++) { adst[q] = asrc[q]; bdst[q] = bsrc[q]; }
        __syncthreads();

        const float4* as4 = (const float4*)As;
        const float4* bs4 = (const float4*)Bs;
#pragma unroll 4
        for (int kk = 0; kk < 16; kk++) {
            float4 a[4], b[4];
#pragma unroll
            for (int i = 0; i < 4; i++) a[i] = as4[(ty + 16 * i) * AS_S4 + kk];
#pragma unroll
            for (int j = 0; j < 4; j++) b[j] = bs4[(tx + 16 * j) * AS_S4 + kk];
#pragma unroll
            for (int i = 0; i < 4; i++)
#pragma unroll
                for (int j = 0; j < 4; j++)
                    acc[i][j] += a[i].x * b[j].x + a[i].y * b[j].y +
                                 a[i].z * b[j].z + a[i].w * b[j].w;
        }
        __syncthreads();
    }
#pragma unroll
    for (int j = 0; j < 4; j++) {
#pragma unroll
        for (int i = 0; i < 4; i++)
            P[(size_t)g * 262144 + (size_t)(jbase + ty + 16 * i) * CC + cbase + tx + 16 * j] =
                acc[i][j];
    }
}

// ---------------------------------------------------------------------------
// Kernel 2: MFMA argmin. Wave owns 64 rows (2 rowsets x 32), X split to
// scaled 2-term fp16 in-register. Per chunk: 8 kk x 6 MFMAs over 4
// independent accumulator chains; E chunks double-buffered in LDS via
// global_load_lds; ||e||^2 enters at scan time from the fp32 table.
__global__ __launch_bounds__(256, 2)
void argmin_mfma_kernel(const float* __restrict__ z,
                        const unsigned short* __restrict__ esw,
                        const float* __restrict__ entab,
                        float* __restrict__ ws_diff,
                        float* __restrict__ ind_f) {
    __shared__ unsigned char ebuf[32768];   // 2 x 16384 B chunk buffers
    const int tid = threadIdx.x;
    const int lane = tid & 63;
    const int wave = tid >> 6;
    const int h5 = lane >> 5, l5 = lane & 31;
    const int rb = blockIdx.x * 256 + wave * 64;

    // X fragments: B-frag for kk holds X[n=l5][k = kk*16 + h5*8 + j]
    half8 x1[2][8], x2[2][8];
    float xn[2];
#pragma unroll
    for (int s = 0; s < 2; s++) {
        const float* zr = z + (size_t)(rb + s * 32 + l5) * D + h5 * 8;
        float ss = 0.f;
#pragma unroll
        for (int kk = 0; kk < 8; kk++) {
            float4 a = *(const float4*)(zr + kk * 16);
            float4 b = *(const float4*)(zr + kk * 16 + 4);
            float v[8] = {a.x, a.y, a.z, a.w, b.x, b.y, b.z, b.w};
            half8 t1, t2;
#pragma unroll
            for (int i = 0; i < 8; i++) {
                ss += v[i] * v[i];
                float vc = (__builtin_fabsf(v[i]) < F16_MINNORM) ? 0.0f : v[i];
                _Float16 h = (_Float16)vc;
                float r = v[i] - (float)h;
                t1[i] = h;
                t2[i] = (_Float16)(r * 2048.0f);
            }
            x1[s][kk] = t1; x2[s][kk] = t2;
        }
        xn[s] = ss;
    }

    float minv[2] = {3.0e38f, 3.0e38f};
    int   mini[2] = {0, 0};

    // stage chunk c into buffer b (16384 B; 4096 B per wave, 4 x 1024 B)
    auto stage = [&](int c, int b) {
        const unsigned char* s = (const unsigned char*)esw + (size_t)c * 16384 +
                                 wave * 4096 + lane * 16;
        unsigned char* d = &ebuf[b * 16384 + wave * 4096];
#pragma unroll
        for (int it = 0; it < 4; it++)
            __builtin_amdgcn_global_load_lds(
                (const __attribute__((address_space(1))) unsigned int*)(s + it * 1024),
                (__attribute__((address_space(3))) unsigned int*)(d + it * 1024),
                16, 0, 0);
    };

    stage(0, 0);
    __syncthreads();   // implicit per-wave vmcnt drain + cross-wave barrier

#pragma unroll 1
    for (int c = 0; c < 16; c++) {
        if (c < 15) stage(c + 1, (c + 1) & 1);
        const unsigned char* ldsb = &ebuf[(c & 1) * 16384];

        // ||e||^2 values for this chunk's 16 acc rows (issued early, used at scan)
        float4 enr[4];
#pragma unroll
        for (int u = 0; u < 4; u++)
            enr[u] = *(const float4*)(entab + c * 32 + h5 * 4 + u * 8);

        f32x16 accA0 = (f32x16)(0.0f), accA1 = (f32x16)(0.0f);
        f32x16 accB0 = (f32x16)(0.0f), accB1 = (f32x16)(0.0f);
#pragma unroll
        for (int kk = 0; kk < 8; kk++) {
            const int fo = kk * 1024 + h5 * 512 + l5 * 16;
            half8 e1 = *(const half8*)(ldsb + fo);
            half8 e2 = *(const half8*)(ldsb + 8192 + fo);
            accA0 = __builtin_amdgcn_mfma_f32_32x32x16_f16(e1, x1[0][kk], accA0, 0, 0, 0);
            accA1 = __builtin_amdgcn_mfma_f32_32x32x16_f16(e1, x1[1][kk], accA1, 0, 0, 0);
            accB0 = __builtin_amdgcn_mfma_f32_32x32x16_f16(e1, x2[0][kk], accB0, 0, 0, 0);
            accB1 = __builtin_amdgcn_mfma_f32_32x32x16_f16(e1, x2[1][kk], accB1, 0, 0, 0);
            accB0 = __builtin_amdgcn_mfma_f32_32x32x16_f16(e2, x1[0][kk], accB0, 0, 0, 0);
            accB1 = __builtin_amdgcn_mfma_f32_32x32x16_f16(e2, x1[1][kk], accB1, 0, 0, 0);
        }

        // scan: dist = accA + 2^-11 * accB + ||e||^2 ; monotone code order
        const int cb2 = c * 32 + h5 * 4;
#pragma unroll
        for (int r = 0; r < 16; r++) {
            const float en = ((const float*)&enr[r >> 2])[r & 3];
            const int cand = cb2 + (r & 3) + 8 * (r >> 2);
            float d0 = fmaf(accB0[r], 4.8828125e-4f, accA0[r]) + en;
            float d1 = fmaf(accB1[r], 4.8828125e-4f, accA1[r]) + en;
            if (d0 < minv[0]) { minv[0] = d0; mini[0] = cand; }
            if (d1 < minv[1]) { minv[1] = d1; mini[1] = cand; }
        }
        __syncthreads();
    }

    // merge the two half-wave code sets for the same x-row (col = lane&31)
#pragma unroll
    for (int s = 0; s < 2; s++) {
        float ov = __shfl_xor(minv[s], 32);
        int oi = __shfl_xor(mini[s], 32);
        if (ov < minv[s] || (ov == minv[s] && oi < mini[s])) { minv[s] = ov; mini[s] = oi; }
    }
    if (lane < 32) {
        ind_f[rb + l5] = (float)mini[0];
        ind_f[rb + 32 + l5] = (float)mini[1];
    }

    // diff partial: ||x||^2 (both k-halves) + min proxy, lanes<32 only
    float xf0 = xn[0] + __shfl_xor(xn[0], 32);
    float xf1 = xn[1] + __shfl_xor(xn[1], 32);
    float v = (lane < 32) ? (xf0 + minv[0] + xf1 + minv[1]) : 0.0f;
#pragma unroll
    for (int off = 32; off; off >>= 1) v += __shfl_down(v, off);
    if (lane == 0) atomicAdd(ws_diff, v);
}

// ---------------------------------------------------------------------------
// Kernel 3: out[m,c] = sum_g P[g][ind[m,g]][c] + b[c]
__global__ void apply_kernel(const float* __restrict__ P,
                             const float* __restrict__ projb,
                             const float* __restrict__ ind_f,
                             float* __restrict__ out) {
    const int tid = threadIdx.x;
    const int m = blockIdx.x * 2 + (tid >> 7);
    const int c4 = tid & 127;

    const float4* pb4 = (const float4*)projb;
    float4 acc = pb4[c4];
    const float4* P4 = (const float4*)P;
#pragma unroll
    for (int g = 0; g < 4; g++) {
        const int ig = (int)ind_f[m * 4 + g];
        float4 p = P4[(size_t)g * 65536 + (size_t)ig * 128 + c4];
        acc.x += p.x; acc.y += p.y; acc.z += p.z; acc.w += p.w;
    }
    ((float4*)out)[(size_t)m * 128 + c4] = acc;
}

// ---------------------------------------------------------------------------
__global__ void finalize_kernel(const float* __restrict__ ws_diff,
                                float* __restrict__ diff_out) {
    // diff = 12.5 * (sum ||x||^2 + sum min(||e||^2 - 2x.e)) / (NROWS*D)
    diff_out[0] = 12.5f * ws_diff[0] * (1.0f / 16777216.0f);
}

// ---------------------------------------------------------------------------
extern "C" void kernel_launch(void* const* d_in, const int* in_sizes, int n_in,
                              void* d_out, int out_size, void* d_ws, size_t ws_size,
                              hipStream_t stream) {
    const float* z     = (const float*)d_in[0];
    const float* embed = (const float*)d_in[1];
    const float* projw = (const float*)d_in[2];
    const float* projb = (const float*)d_in[3];

    float* out      = (float*)d_out;
    float* diff_out = out + OUT_ELEMS;
    float* ind_f    = out + OUT_ELEMS + 1;

    char* wsb = (char*)d_ws;
    float* ws_diff = (float*)wsb;
    float* entab = (float*)(wsb + 1024);
    unsigned short* esw = (unsigned short*)(wsb + 4096);
    float* P = (float*)(wsb + 266240);

    eprep_kernel<<<16, 256, 0, stream>>>(embed, esw, entab, ws_diff);
    pgemm_kernel<<<dim3(8, 8, 4), 256, 0, stream>>>(embed, projw, P);
    argmin_mfma_kernel<<<NROWS / 256, 256, 0, stream>>>(z, esw, entab, ws_diff, ind_f);
    apply_kernel<<<32768 / 2, 256, 0, stream>>>(P, projb, ind_f, out);
    finalize_kernel<<<1, 1, 0, stream>>>(ws_diff, diff_out);
}

// Round 5
// 218.910 us; speedup vs baseline: 3.2191x; 1.0514x over previous
//
#include <hip/hip_runtime.h>

// Problem constants (B=8, H=4096, C=512, GROUPS=4)
constexpr int D         = 128;        // d = C/GROUPS
constexpr int NE        = 512;        // n_embed
constexpr int NROWS     = 131072;     // B*H*GROUPS
constexpr int CC        = 512;        // C
constexpr int OUT_ELEMS = 16777216;   // MROWS*CC

// ws layout (bytes):
//   [0]                 : float diff accumulator
//   [1024, +2048)       : entab - ||e_j||^2 fp32, 512 floats
//   [4096, +262144)     : esw - 16 chunks x 16384 B:
//        [0,8192)   Eh : fp16(-2E), MFMA A-frag layout
//        [8192,16384) El: fp16((-2E - Eh)*2048)
//   [266240, +4194304)  : P[4][512][512] fp32

using half8  = __attribute__((ext_vector_type(8))) _Float16;
using f32x16 = __attribute__((ext_vector_type(16))) float;

// fp16 min normal: leading term below this is zeroed so the (possibly
// flushed-by-MFMA) denormal carries nothing; residual then holds it all.
#define F16_MINNORM 6.103515625e-05f

// ---------------------------------------------------------------------------
// Kernel 0: scaled 2-term fp16 split of -2E into MFMA A-frag layout + fp32
// ||e||^2 table; zero the diff accumulator.
__global__ void eprep_kernel(const float* __restrict__ embed,
                             unsigned short* __restrict__ esw,
                             float* __restrict__ entab,
                             float* __restrict__ ws_diff) {
    const int chunk = blockIdx.x;
    const int tid = threadIdx.x;
    const int cl = tid >> 3;    // code in chunk (0..31) == A-row == lane&31
    const int seg = tid & 7;    // k-group of 16 (== kk)
    const float* src = embed + (size_t)(chunk * 32 + cl) * D + seg * 16;
    unsigned short* cb = esw + (size_t)chunk * 8192;  // shorts per chunk

    float ss = 0.f;
#pragma unroll
    for (int g2 = 0; g2 < 2; g2++) {       // g2 == h5 (k-half of the MFMA slice)
        float4 a = ((const float4*)src)[g2 * 2 + 0];
        float4 b = ((const float4*)src)[g2 * 2 + 1];
        float v[8] = {a.x, a.y, a.z, a.w, b.x, b.y, b.z, b.w};
        half8 t1, t2;
#pragma unroll
        for (int i = 0; i < 8; i++) {
            ss += v[i] * v[i];
            float m2 = -2.0f * v[i];
            float m2c = (__builtin_fabsf(m2) < F16_MINNORM) ? 0.0f : m2;
            _Float16 h = (_Float16)m2c;
            float r = m2 - (float)h;
            t1[i] = h;
            t2[i] = (_Float16)(r * 2048.0f);   // scaled residual, fp16-normal
        }
        const int idx = seg * 512 + g2 * 256 + cl * 8;
        *(half8*)(cb + idx) = t1;          // Eh
        *(half8*)(cb + 4096 + idx) = t2;   // El
    }
    ss += __shfl_down(ss, 4, 8);
    ss += __shfl_down(ss, 2, 8);
    ss += __shfl_down(ss, 1, 8);
    if (seg == 0) entab[chunk * 32 + cl] = ss;
    if (chunk == 0 && tid == 0) ws_diff[0] = 0.0f;
}

// ---------------------------------------------------------------------------
// Kernel 1: P[g][j][c] = sum_k E[j,k] * W[c, g*128+k]   (fp32, 134 M MAC)
#define AS_STRIDE 68
#define AS_S4 17

__launch_bounds__(256, 4)
__global__ void pgemm_kernel(const float* __restrict__ embed,
                             const float* __restrict__ projw,
                             float* __restrict__ P) {
    __shared__ float As[64 * AS_STRIDE];
    __shared__ float Bs[64 * AS_STRIDE];
    const int tid = threadIdx.x;
    const int cbase = blockIdx.x * 64;   // 8
    const int jbase = blockIdx.y * 64;   // 8
    const int g = blockIdx.z;            // 4
    const int tx = tid & 15, ty = tid >> 4;
    const int r = tid >> 2, seg = tid & 3;

    float acc[4][4];
#pragma unroll
    for (int i = 0; i < 4; i++)
#pragma unroll
        for (int j = 0; j < 4; j++) acc[i][j] = 0.f;

    for (int kb = 0; kb < D; kb += 64) {
        const float4* asrc = (const float4*)(embed + (size_t)(jbase + r) * D + kb + seg * 16);
        const float4* bsrc = (const float4*)(projw + (size_t)(cbase + r) * CC + g * D + kb + seg * 16);
        float4* adst = (float4*)&As[r * AS_STRIDE + seg * 16];
        float4* bdst = (float4*)&Bs[r * AS_STRIDE + seg * 16];
#pragma unroll
        for (int q = 0; q < 4; q++) { adst[q] = asrc[q]; bdst[q] = bsrc[q]; }
        __syncthreads();

        const float4* as4 = (const float4*)As;
        const float4* bs4 = (const float4*)Bs;
#pragma unroll 4
        for (int kk = 0; kk < 16; kk++) {
            float4 a[4], b[4];
#pragma unroll
            for (int i = 0; i < 4; i++) a[i] = as4[(ty + 16 * i) * AS_S4 + kk];
#pragma unroll
            for (int j = 0; j < 4; j++) b[j] = bs4[(tx + 16 * j) * AS_S4 + kk];
#pragma unroll
            for (int i = 0; i < 4; i++)
#pragma unroll
                for (int j = 0; j < 4; j++)
                    acc[i][j] += a[i].x * b[j].x + a[i].y * b[j].y +
                                 a[i].z * b[j].z + a[i].w * b[j].w;
        }
        __syncthreads();
    }
#pragma unroll
    for (int j = 0; j < 4; j++) {
#pragma unroll
        for (int i = 0; i < 4; i++)
            P[(size_t)g * 262144 + (size_t)(jbase + ty + 16 * i) * CC + cbase + tx + 16 * j] =
                acc[i][j];
    }
}

// ---------------------------------------------------------------------------
// Kernel 2: fused MFMA argmin + projection epilogue.
// Wave owns 32 rows (X frags: 64 VGPR, no spill). Block = 128 rows = 32 m.
// After argmin, indices go to LDS and the block emits out[mb..mb+32) directly
// via P-gather (P is L2-resident).
__global__ __launch_bounds__(256, 3)
void argmin_fused_kernel(const float* __restrict__ z,
                         const unsigned short* __restrict__ esw,
                         const float* __restrict__ entab,
                         const float* __restrict__ P,
                         const float* __restrict__ projb,
                         float* __restrict__ ws_diff,
                         float* __restrict__ ind_f,
                         float* __restrict__ out) {
    __shared__ unsigned char ebuf[32768];   // 2 x 16384 B chunk buffers
    __shared__ int ind_s[128];
    const int tid = threadIdx.x;
    const int lane = tid & 63;
    const int wave = tid >> 6;
    const int h5 = lane >> 5, l5 = lane & 31;
    const int rb = blockIdx.x * 128 + wave * 32;

    // X fragments: B-frag for kk holds X[n=l5][k = kk*16 + h5*8 + j]
    half8 x1[8], x2[8];
    float xn = 0.f;
    {
        const float* zr = z + (size_t)(rb + l5) * D + h5 * 8;
#pragma unroll
        for (int kk = 0; kk < 8; kk++) {
            float4 a = *(const float4*)(zr + kk * 16);
            float4 b = *(const float4*)(zr + kk * 16 + 4);
            float v[8] = {a.x, a.y, a.z, a.w, b.x, b.y, b.z, b.w};
            half8 t1, t2;
#pragma unroll
            for (int i = 0; i < 8; i++) {
                xn += v[i] * v[i];
                float vc = (__builtin_fabsf(v[i]) < F16_MINNORM) ? 0.0f : v[i];
                _Float16 h = (_Float16)vc;
                float r = v[i] - (float)h;
                t1[i] = h;
                t2[i] = (_Float16)(r * 2048.0f);
            }
            x1[kk] = t1; x2[kk] = t2;
        }
    }

    float minv = 3.0e38f;
    int   mini = 0;

    // stage chunk c into buffer b (16384 B; 4096 B per wave, 4 x 1024 B)
    auto stage = [&](int c, int b) {
        const unsigned char* s = (const unsigned char*)esw + (size_t)c * 16384 +
                                 wave * 4096 + lane * 16;
        unsigned char* d = &ebuf[b * 16384 + wave * 4096];
#pragma unroll
        for (int it = 0; it < 4; it++)
            __builtin_amdgcn_global_load_lds(
                (const __attribute__((address_space(1))) unsigned int*)(s + it * 1024),
                (__attribute__((address_space(3))) unsigned int*)(d + it * 1024),
                16, 0, 0);
    };

    stage(0, 0);
    __syncthreads();

#pragma unroll 1
    for (int c = 0; c < 16; c++) {
        if (c < 15) stage(c + 1, (c + 1) & 1);
        const unsigned char* ldsb = &ebuf[(c & 1) * 16384];

        // ||e||^2 for this chunk's 16 acc rows (used at scan time, fp32)
        float4 enr[4];
#pragma unroll
        for (int u = 0; u < 4; u++)
            enr[u] = *(const float4*)(entab + c * 32 + h5 * 4 + u * 8);

        f32x16 accA = (f32x16)(0.0f), accB = (f32x16)(0.0f);
#pragma unroll
        for (int kk = 0; kk < 8; kk++) {
            const int fo = kk * 1024 + h5 * 512 + l5 * 16;
            half8 e1 = *(const half8*)(ldsb + fo);
            half8 e2 = *(const half8*)(ldsb + 8192 + fo);
            accA = __builtin_amdgcn_mfma_f32_32x32x16_f16(e1, x1[kk], accA, 0, 0, 0);
            accB = __builtin_amdgcn_mfma_f32_32x32x16_f16(e1, x2[kk], accB, 0, 0, 0);
            accB = __builtin_amdgcn_mfma_f32_32x32x16_f16(e2, x1[kk], accB, 0, 0, 0);
        }

        // scan: dist = accA + 2^-11 * accB + ||e||^2 ; monotone code order
        const int cb2 = c * 32 + h5 * 4;
#pragma unroll
        for (int r = 0; r < 16; r++) {
            const float en = ((const float*)&enr[r >> 2])[r & 3];
            const int cand = cb2 + (r & 3) + 8 * (r >> 2);
            float d0 = fmaf(accB[r], 4.8828125e-4f, accA[r]) + en;
            if (d0 < minv) { minv = d0; mini = cand; }  // strict < keeps first
        }
        __syncthreads();
    }

    // merge the two half-wave code sets for the same x-row (col = lane&31)
    {
        float ov = __shfl_xor(minv, 32);
        int oi = __shfl_xor(mini, 32);
        if (ov < minv || (ov == minv && oi < mini)) { minv = ov; mini = oi; }
    }
    if (lane < 32) {
        ind_f[rb + l5] = (float)mini;
        ind_s[wave * 32 + l5] = mini;
    }

    // diff partial: ||x||^2 (both k-halves) + min proxy, lanes<32 only
    float xfull = xn + __shfl_xor(xn, 32);
    float v = (lane < 32) ? (xfull + minv) : 0.0f;
#pragma unroll
    for (int off = 32; off; off >>= 1) v += __shfl_down(v, off);
    if (lane == 0) atomicAdd(ws_diff, v);

    __syncthreads();   // ind_s ready

    // ---- fused projection epilogue: out[m,c] = sum_g P[g][ind[m,g]][c] + b[c]
    // block covers m in [mb, mb+32); row (m,g) -> ind_s[(m-mb)*4+g]
    const int mb = blockIdx.x * 32;
    const int c4 = tid & 127;
    const int mh = (tid >> 7) * 16;   // 0 or 16
    const float4 bias = ((const float4*)projb)[c4];
    const float4* P4 = (const float4*)P;
#pragma unroll 4
    for (int u = 0; u < 16; u++) {
        const int ml = mh + u;
        float4 acc = bias;
#pragma unroll
        for (int g = 0; g < 4; g++) {
            const int ig = ind_s[ml * 4 + g];
            float4 p = P4[(size_t)g * 65536 + (size_t)ig * 128 + c4];
            acc.x += p.x; acc.y += p.y; acc.z += p.z; acc.w += p.w;
        }
        ((float4*)out)[(size_t)(mb + ml) * 128 + c4] = acc;
    }
}

// ---------------------------------------------------------------------------
__global__ void finalize_kernel(const float* __restrict__ ws_diff,
                                float* __restrict__ diff_out) {
    // diff = 12.5 * (sum ||x||^2 + sum min(||e||^2 - 2x.e)) / (NROWS*D)
    diff_out[0] = 12.5f * ws_diff[0] * (1.0f / 16777216.0f);
}

// ---------------------------------------------------------------------------
extern "C" void kernel_launch(void* const* d_in, const int* in_sizes, int n_in,
                              void* d_out, int out_size, void* d_ws, size_t ws_size,
                              hipStream_t stream) {
    const float* z     = (const float*)d_in[0];
    const float* embed = (const float*)d_in[1];
    const float* projw = (const float*)d_in[2];
    const float* projb = (const float*)d_in[3];

    float* out      = (float*)d_out;
    float* diff_out = out + OUT_ELEMS;
    float* ind_f    = out + OUT_ELEMS + 1;

    char* wsb = (char*)d_ws;
    float* ws_diff = (float*)wsb;
    float* entab = (float*)(wsb + 1024);
    unsigned short* esw = (unsigned short*)(wsb + 4096);
    float* P = (float*)(wsb + 266240);

    eprep_kernel<<<16, 256, 0, stream>>>(embed, esw, entab, ws_diff);
    pgemm_kernel<<<dim3(8, 8, 4), 256, 0, stream>>>(embed, projw, P);
    argmin_fused_kernel<<<NROWS / 128, 256, 0, stream>>>(z, esw, entab, P, projb,
                                                         ws_diff, ind_f, out);
    finalize_kernel<<<1, 1, 0, stream>>>(ws_diff, diff_out);
}